// Round 9
// baseline (103.430 us; speedup 1.0000x reference)
//
#include <hip/hip_runtime.h>
#include <math.h>

// (B,C,H,W) = (16,256,80,80), GROUPS=32 -> 512 group-instances of 8x80x80
constexpr int CG   = 8;
constexpr int Hh   = 80;
constexpr int HW   = 6400;         // 80*80
constexpr int NG   = 512;          // B*GROUPS
constexpr int NCH  = NG * CG;      // 4096 channels
constexpr int PP   = NCH * 80;     // 327680 floats per pool array
constexpr float EPSf = 1e-5f;
// ws: pools only, [a*PP + bgc*80 + p], a = 0:mean_h 1:mean_w 2:max_h 3:max_w

__device__ __forceinline__ float sigmoidf(float v) {
    return 1.0f / (1.0f + __expf(-v));
}

// ---------------- K1: per-channel row/col mean+max pools (cold HBM) --------
__global__ __launch_bounds__(256) void k_pool(const float* __restrict__ x,
                                              float* __restrict__ ws) {
    const int bgc = blockIdx.x;                 // 0..4095
    const float* base = x + (size_t)bgc * HW;
    __shared__ float tile[Hh * 84];             // pad stride 84

    for (int v = threadIdx.x; v < 1600; v += 256) {
        int h  = v / 20;
        int w0 = (v % 20) * 4;
        float4 d = ((const float4*)base)[v];
        *(float4*)&tile[h * 84 + w0] = d;
    }
    __syncthreads();

    const int t = threadIdx.x;
    if (t < 80) {
        // row t: mean/max over w  (waves 0-1)
        float s = 0.f, m = -INFINITY;
        const float4* r = (const float4*)&tile[t * 84];
        #pragma unroll
        for (int i = 0; i < 20; i++) {
            float4 d = r[i];
            s += d.x + d.y + d.z + d.w;
            m = fmaxf(m, fmaxf(fmaxf(d.x, d.y), fmaxf(d.z, d.w)));
        }
        ws[0 * PP + bgc * 80 + t] = s * (1.f / 80.f);
        ws[2 * PP + bgc * 80 + t] = m;
    } else if (t >= 128 && t < 208) {
        // col (t-128): mean/max over h  (waves 2-3)
        const int c = t - 128;
        float s2 = 0.f, m2 = -INFINITY;
        #pragma unroll 8
        for (int i = 0; i < 80; i++) {
            float v = tile[i * 84 + c];
            s2 += v;
            m2 = fmaxf(m2, v);
        }
        ws[1 * PP + bgc * 80 + c] = s2 * (1.f / 80.f);
        ws[3 * PP + bgc * 80 + c] = m2;
    }
}

// ---- K2: gates + stats + finalize + HALF the output per block -------------
// 1024 blocks (2 per group) x 512 threads: grid no longer caps occupancy
// (4 blocks/CU x 8 waves = 32 waves/CU). Gates+stats+finalize are computed
// redundantly by both halves (stats re-read of x is L3-resident: R8 showed
// FETCH 59 MB << 105 MB); each block writes only its spatial half of out.
__global__ __launch_bounds__(512, 8) void k_rest(
    const float* __restrict__ x,
    const float* __restrict__ conv_w,
    const float* __restrict__ conv_b,
    const float* __restrict__ gnw,
    const float* __restrict__ gnb,
    const float* __restrict__ ws,
    float* __restrict__ out)
{
    const int bg   = blockIdx.x >> 1;      // 0..511
    const int half = blockIdx.x & 1;       // which spatial half of out
    const int tid  = threadIdx.x;          // 0..511

    __shared__ float pl[2560];             // pools [a][c][p]
    __shared__ float g[2560];              // gates  [a][c][p]
    __shared__ float wsm[64];
    __shared__ float cbs[8];
    __shared__ float red[8][6];            // one wave per channel
    __shared__ float Axs[8], Bxs[8], Ays[8], Bys[8], ymaxs[8], cHx[8], cHy[8];
    __shared__ float kcs;

    if (tid < 64) wsm[tid] = conv_w[tid];
    if (tid < 8)  cbs[tid] = conv_b[tid];
    #pragma unroll
    for (int i = 0; i < 5; ++i) {
        const int e = tid + i * 512;
        if (e < 2560) {
            const int a = e / 640, rem = e % 640, c = rem / 80, p = rem % 80;
            pl[e] = ws[a * PP + (bg * 8 + c) * 80 + p];
        }
    }
    __syncthreads();

    // gates = sigmoid(8x8 conv of pools)
    #pragma unroll
    for (int i = 0; i < 5; ++i) {
        const int e = tid + i * 512;
        if (e < 2560) {
            const int a = e / 640, rem = e % 640, c = rem / 80, p = rem % 80;
            float acc = cbs[c];
            #pragma unroll
            for (int cc = 0; cc < 8; ++cc)
                acc += wsm[c * 8 + cc] * pl[a * 640 + cc * 80 + p];
            g[e] = sigmoidf(acc);
        }
    }
    __syncthreads();

    // ---- stats: one wave per channel, stream x from L2/L3 -----------------
    const float* base = x + (size_t)bg * CG * HW;
    {
        const int c = tid >> 6, lane = tid & 63;
        const float* cb_ = base + c * HW;
        float s1x = 0.f, s2x = 0.f, s1y = 0.f, s2y = 0.f;
        float my = -INFINITY, ny = INFINITY;
        for (int j = 0; j < 25; ++j) {
            const int v = lane + j * 64;           // exactly covers 1600 f4
            float4 d = ((const float4*)cb_)[v];
            const int h = v / 20, w0 = (v % 20) * 4;
            const float ghx = g[0 * 640 + c * 80 + h];
            const float ghy = g[2 * 640 + c * 80 + h];
            const float4 gwx = *(const float4*)&g[1 * 640 + c * 80 + w0];
            const float4 gwy = *(const float4*)&g[3 * 640 + c * 80 + w0];
            const float dd[4]  = {d.x, d.y, d.z, d.w};
            const float gx4[4] = {gwx.x, gwx.y, gwx.z, gwx.w};
            const float gy4[4] = {gwy.x, gwy.y, gwy.z, gwy.w};
            #pragma unroll
            for (int k = 0; k < 4; ++k) {
                const float tx = dd[k] * ghx * gx4[k];
                const float ty = dd[k] * ghy * gy4[k];
                s1x += tx; s2x += tx * tx;
                s1y += ty; s2y += ty * ty;
                my = fmaxf(my, ty); ny = fminf(ny, ty);
            }
        }
        #pragma unroll
        for (int off = 32; off > 0; off >>= 1) {
            s1x += __shfl_down(s1x, off);
            s2x += __shfl_down(s2x, off);
            s1y += __shfl_down(s1y, off);
            s2y += __shfl_down(s2y, off);
            my = fmaxf(my, __shfl_down(my, off));
            ny = fminf(ny, __shfl_down(ny, off));
        }
        if (lane == 0) {
            red[c][0] = s1x; red[c][1] = s2x; red[c][2] = s1y;
            red[c][3] = s2y; red[c][4] = my;  red[c][5] = ny;
        }
    }
    __syncthreads();

    // ---- finalize affine-norm constants -----------------------------------
    if (tid < 8) {
        const float s1x = red[tid][0], s2x = red[tid][1];
        const float s1y = red[tid][2], s2y = red[tid][3];
        const float my  = red[tid][4], ny  = red[tid][5];
        const float w = gnw[tid], b = gnb[tid];
        const float mux  = s1x * (1.f / 6400.f);
        const float varx = s2x * (1.f / 6400.f) - mux * mux;
        const float ax   = rsqrtf(varx + EPSf) * w;
        Axs[tid] = ax; Bxs[tid] = b - mux * ax;
        const float muy  = s1y * (1.f / 6400.f);
        const float vary = s2y * (1.f / 6400.f) - muy * muy;
        const float ay   = rsqrtf(vary + EPSf) * w;
        Ays[tid] = ay; Bys[tid] = b - muy * ay;
        ymaxs[tid] = (ay >= 0.f ? my : ny) * ay + Bys[tid];
    }
    __syncthreads();
    if (tid == 0) {
        // x12 = softmax(gn_b): HW-mean of an HW-normalized tensor is gn_b.
        float x12[8], y12[8];
        float mb = -INFINITY;
        for (int c = 0; c < 8; ++c) mb = fmaxf(mb, gnb[c]);
        float se = 0.f;
        for (int c = 0; c < 8; ++c) { x12[c] = __expf(gnb[c] - mb); se += x12[c]; }
        float inv = 1.f / se;
        for (int c = 0; c < 8; ++c) x12[c] *= inv;
        float m2 = -INFINITY;
        for (int c = 0; c < 8; ++c) m2 = fmaxf(m2, ymaxs[c]);
        se = 0.f;
        for (int c = 0; c < 8; ++c) { y12[c] = __expf(ymaxs[c] - m2); se += y12[c]; }
        inv = 1.f / se;
        float kc = 0.f;
        for (int c = 0; c < 8; ++c) {
            y12[c] *= inv;
            cHx[c] = y12[c] * Axs[c];   // scales mean-branch h-gate
            cHy[c] = x12[c] * Ays[c];   // scales max-branch  h-gate
            kc += x12[c] * Bys[c] + y12[c] * Bxs[c];
        }
        kcs = kc;
    }
    __syncthreads();
    for (int e = tid; e < 640; e += 512) {
        g[e]        *= cHx[e / 80];          // a=0 (mean-branch h)
        g[1280 + e] *= cHy[e / 80];          // a=2 (max-branch h)
    }
    __syncthreads();

    // ---- output: this block's spatial half (800 float4 slots) -------------
    const float kc = kcs;
    float* ob = out + (size_t)bg * CG * HW;
    #pragma unroll
    for (int i = 0; i < 2; ++i) {
        const int r = tid + i * 512;
        if (r < 800) {
            const int v = half * 800 + r;
            const int h = v / 20, w0 = (v % 20) * 4;
            float4 gxv[8];
            #pragma unroll
            for (int c = 0; c < 8; ++c)
                gxv[c] = ((const float4*)(base + c * HW))[v];

            float s0 = kc, s1 = kc, s2 = kc, s3 = kc;
            #pragma unroll
            for (int c = 0; c < 8; ++c) {
                const float chx = g[c * 80 + h];
                const float chy = g[1280 + c * 80 + h];
                const float4 cwx = *(const float4*)&g[640  + c * 80 + w0];
                const float4 cwy = *(const float4*)&g[1920 + c * 80 + w0];
                s0 += gxv[c].x * (chy * cwy.x + chx * cwx.x);
                s1 += gxv[c].y * (chy * cwy.y + chx * cwx.y);
                s2 += gxv[c].z * (chy * cwy.z + chx * cwx.z);
                s3 += gxv[c].w * (chy * cwy.w + chx * cwx.w);
            }
            s0 = sigmoidf(s0); s1 = sigmoidf(s1);
            s2 = sigmoidf(s2); s3 = sigmoidf(s3);
            #pragma unroll
            for (int c = 0; c < 8; ++c) {
                float4 o;
                o.x = gxv[c].x * s0; o.y = gxv[c].y * s1;
                o.z = gxv[c].z * s2; o.w = gxv[c].w * s3;
                ((float4*)(ob + c * HW))[v] = o;
            }
        }
    }
}

extern "C" void kernel_launch(void* const* d_in, const int* in_sizes, int n_in,
                              void* d_out, int out_size, void* d_ws, size_t ws_size,
                              hipStream_t stream) {
    const float* x      = (const float*)d_in[0];
    const float* conv_w = (const float*)d_in[1];
    const float* conv_b = (const float*)d_in[2];
    const float* gn_w   = (const float*)d_in[3];
    const float* gn_b   = (const float*)d_in[4];
    float* out = (float*)d_out;
    float* ws  = (float*)d_ws;   // 4*PP floats ~ 5.2 MB

    k_pool<<<NCH,    256, 0, stream>>>(x, ws);
    k_rest<<<NG * 2, 512, 0, stream>>>(x, conv_w, conv_b, gn_w, gn_b, ws, out);
}

// Round 10
// 77.259 us; speedup vs baseline: 1.3388x; 1.3388x over previous
//
#include <hip/hip_runtime.h>
#include <math.h>

// (B,C,H,W) = (16,256,80,80), GROUPS=32 -> 512 group-instances of 8x80x80
constexpr int CG = 8;
constexpr int HW = 6400;           // 80*80
constexpr int NG = 512;            // B*GROUPS
constexpr float EPSf = 1e-5f;

__device__ __forceinline__ float sigmoidf(float v) {
    return 1.0f / (1.0f + __expf(-v));
}

// Single fused kernel: one block per group, 512 threads (8 waves).
// Phase A1: col pools (reduce over h) — lane<->w coalesced COLD read of x.
// Phase A2: row pools (reduce over w) — per-thread contiguous row, L2/L3-hot.
// No LDS tile, no per-channel barriers (R3 had 16; this has ~6 total).
// B: gates = sigmoid(8x8 conv of pools); C: gated stats (L3 re-read);
// D: finalize + fold coefs; E: weights -> sigmoid -> out (L3 re-read + write).
__global__ __launch_bounds__(512, 4) void k_fused(
    const float* __restrict__ x,
    const float* __restrict__ conv_w,
    const float* __restrict__ conv_b,
    const float* __restrict__ gnw,
    const float* __restrict__ gnb,
    float* __restrict__ out)
{
    const int bg  = blockIdx.x;            // 0..511
    const int tid = threadIdx.x;           // 0..511

    __shared__ float pl[2560];             // pools [a][c][p]: a0=mh a1=mw a2=xh a3=xw
    __shared__ float g[2560];              // gates (h-gates coef-folded later)
    __shared__ float wsm[64];
    __shared__ float cbs[8];
    __shared__ float red[8][6];            // one wave per channel
    __shared__ float Axs[8], Bxs[8], Ays[8], Bys[8], ymaxs[8], cHx[8], cHy[8];
    __shared__ float kcs;

    if (tid < 64) wsm[tid] = conv_w[tid];
    if (tid < 8)  cbs[tid] = conv_b[tid];

    const float* base = x + (size_t)bg * CG * HW;

    // ---- Phase A1: col pools (mean/max over h), coalesced cold read -------
    for (int e = tid; e < 640; e += 512) {
        const int c = e / 80, w = e % 80;
        const float* p = base + c * HW + w;
        float s = 0.f, m = -INFINITY;
        #pragma unroll 4
        for (int h = 0; h < 80; ++h) {
            const float v = p[h * 80];
            s += v;
            m = fmaxf(m, v);
        }
        pl[1 * 640 + c * 80 + w] = s * (1.f / 80.f);
        pl[3 * 640 + c * 80 + w] = m;
    }

    // ---- Phase A2: row pools (mean/max over w), contiguous rows (L2/L3) ---
    for (int e = tid; e < 640; e += 512) {
        const int c = e / 80, h = e % 80;
        const float4* p = (const float4*)(base + c * HW + h * 80);
        float s = 0.f, m = -INFINITY;
        #pragma unroll
        for (int k = 0; k < 20; ++k) {
            const float4 d = p[k];
            s += (d.x + d.y) + (d.z + d.w);
            m = fmaxf(m, fmaxf(fmaxf(d.x, d.y), fmaxf(d.z, d.w)));
        }
        pl[0 * 640 + c * 80 + h] = s * (1.f / 80.f);
        pl[2 * 640 + c * 80 + h] = m;
    }
    __syncthreads();

    // ---- Phase B: gates = sigmoid(8x8 conv of pools) ----------------------
    #pragma unroll
    for (int i = 0; i < 5; ++i) {
        const int e = tid + i * 512;
        if (e < 2560) {
            const int a = e / 640, rem = e % 640, c = rem / 80, p = rem % 80;
            float acc = cbs[c];
            #pragma unroll
            for (int cc = 0; cc < 8; ++cc)
                acc += wsm[c * 8 + cc] * pl[a * 640 + cc * 80 + p];
            g[e] = sigmoidf(acc);
        }
    }
    __syncthreads();

    // ---- Phase C: per-channel gated stats (one wave/ch, L3 re-read) -------
    {
        const int c = tid >> 6, lane = tid & 63;
        const float* cb_ = base + c * HW;
        float s1x = 0.f, s2x = 0.f, s1y = 0.f, s2y = 0.f;
        float my = -INFINITY, ny = INFINITY;
        for (int j = 0; j < 25; ++j) {
            const int v = lane + j * 64;           // exactly covers 1600 f4
            float4 d = ((const float4*)cb_)[v];
            const int h = v / 20, w0 = (v % 20) * 4;
            const float ghx = g[0 * 640 + c * 80 + h];
            const float ghy = g[2 * 640 + c * 80 + h];
            const float4 gwx = *(const float4*)&g[1 * 640 + c * 80 + w0];
            const float4 gwy = *(const float4*)&g[3 * 640 + c * 80 + w0];
            const float dd[4]  = {d.x, d.y, d.z, d.w};
            const float gx4[4] = {gwx.x, gwx.y, gwx.z, gwx.w};
            const float gy4[4] = {gwy.x, gwy.y, gwy.z, gwy.w};
            #pragma unroll
            for (int k = 0; k < 4; ++k) {
                const float tx = dd[k] * ghx * gx4[k];
                const float ty = dd[k] * ghy * gy4[k];
                s1x += tx; s2x += tx * tx;
                s1y += ty; s2y += ty * ty;
                my = fmaxf(my, ty); ny = fminf(ny, ty);
            }
        }
        #pragma unroll
        for (int off = 32; off > 0; off >>= 1) {
            s1x += __shfl_down(s1x, off);
            s2x += __shfl_down(s2x, off);
            s1y += __shfl_down(s1y, off);
            s2y += __shfl_down(s2y, off);
            my = fmaxf(my, __shfl_down(my, off));
            ny = fminf(ny, __shfl_down(ny, off));
        }
        if (lane == 0) {
            red[c][0] = s1x; red[c][1] = s2x; red[c][2] = s1y;
            red[c][3] = s2y; red[c][4] = my;  red[c][5] = ny;
        }
    }
    __syncthreads();

    // ---- Phase D: finalize affine-norm constants + softmaxes + fold -------
    if (tid < 8) {
        const float s1x = red[tid][0], s2x = red[tid][1];
        const float s1y = red[tid][2], s2y = red[tid][3];
        const float my  = red[tid][4], ny  = red[tid][5];
        const float w = gnw[tid], b = gnb[tid];
        const float mux  = s1x * (1.f / 6400.f);
        const float varx = s2x * (1.f / 6400.f) - mux * mux;
        const float ax   = rsqrtf(varx + EPSf) * w;
        Axs[tid] = ax; Bxs[tid] = b - mux * ax;
        const float muy  = s1y * (1.f / 6400.f);
        const float vary = s2y * (1.f / 6400.f) - muy * muy;
        const float ay   = rsqrtf(vary + EPSf) * w;
        Ays[tid] = ay; Bys[tid] = b - muy * ay;
        ymaxs[tid] = (ay >= 0.f ? my : ny) * ay + Bys[tid];
    }
    __syncthreads();
    if (tid == 0) {
        // x12 = softmax(gn_b): HW-mean of an HW-normalized tensor is gn_b.
        float x12[8], y12[8];
        float mb = -INFINITY;
        for (int c = 0; c < 8; ++c) mb = fmaxf(mb, gnb[c]);
        float se = 0.f;
        for (int c = 0; c < 8; ++c) { x12[c] = __expf(gnb[c] - mb); se += x12[c]; }
        float inv = 1.f / se;
        for (int c = 0; c < 8; ++c) x12[c] *= inv;
        float m2 = -INFINITY;
        for (int c = 0; c < 8; ++c) m2 = fmaxf(m2, ymaxs[c]);
        se = 0.f;
        for (int c = 0; c < 8; ++c) { y12[c] = __expf(ymaxs[c] - m2); se += y12[c]; }
        inv = 1.f / se;
        float kc = 0.f;
        for (int c = 0; c < 8; ++c) {
            y12[c] *= inv;
            cHx[c] = y12[c] * Axs[c];   // scales mean-branch h-gate
            cHy[c] = x12[c] * Ays[c];   // scales max-branch  h-gate
            kc += x12[c] * Bys[c] + y12[c] * Bxs[c];
        }
        kcs = kc;
    }
    __syncthreads();
    for (int e = tid; e < 640; e += 512) {
        g[e]        *= cHx[e / 80];          // a=0 (mean-branch h)
        g[1280 + e] *= cHy[e / 80];          // a=2 (max-branch h)
    }
    __syncthreads();

    // ---- Phase E: weights -> sigmoid -> output (L3 re-read + HBM write) ---
    const float kc = kcs;
    float* ob = out + (size_t)bg * CG * HW;
    #pragma unroll
    for (int i = 0; i < 4; ++i) {
        const int v = tid + i * 512;
        if (v < 1600) {
            const int h = v / 20, w0 = (v % 20) * 4;
            float4 gxv[8];
            #pragma unroll
            for (int c = 0; c < 8; ++c)
                gxv[c] = ((const float4*)(base + c * HW))[v];

            float s0 = kc, s1 = kc, s2 = kc, s3 = kc;
            #pragma unroll
            for (int c = 0; c < 8; ++c) {
                const float chx = g[c * 80 + h];
                const float chy = g[1280 + c * 80 + h];
                const float4 cwx = *(const float4*)&g[640  + c * 80 + w0];
                const float4 cwy = *(const float4*)&g[1920 + c * 80 + w0];
                s0 += gxv[c].x * (chy * cwy.x + chx * cwx.x);
                s1 += gxv[c].y * (chy * cwy.y + chx * cwx.y);
                s2 += gxv[c].z * (chy * cwy.z + chx * cwx.z);
                s3 += gxv[c].w * (chy * cwy.w + chx * cwx.w);
            }
            s0 = sigmoidf(s0); s1 = sigmoidf(s1);
            s2 = sigmoidf(s2); s3 = sigmoidf(s3);
            #pragma unroll
            for (int c = 0; c < 8; ++c) {
                float4 o;
                o.x = gxv[c].x * s0; o.y = gxv[c].y * s1;
                o.z = gxv[c].z * s2; o.w = gxv[c].w * s3;
                ((float4*)(ob + c * HW))[v] = o;
            }
        }
    }
}

extern "C" void kernel_launch(void* const* d_in, const int* in_sizes, int n_in,
                              void* d_out, int out_size, void* d_ws, size_t ws_size,
                              hipStream_t stream) {
    const float* x      = (const float*)d_in[0];
    const float* conv_w = (const float*)d_in[1];
    const float* conv_b = (const float*)d_in[2];
    const float* gn_w   = (const float*)d_in[3];
    const float* gn_b   = (const float*)d_in[4];
    float* out = (float*)d_out;
    (void)d_ws; (void)ws_size;

    k_fused<<<NG, 512, 0, stream>>>(x, conv_w, conv_b, gn_w, gn_b, out);
}